// Round 5
// baseline (380.597 us; speedup 1.0000x reference)
//
#include <hip/hip_runtime.h>

#define G_N 40000
#define P_N 5
#define PIX 65536   // 256*256
#define XP 136      // MLP LDS activation row stride (shorts)

typedef short short8 __attribute__((ext_vector_type(8)));
typedef short short4v __attribute__((ext_vector_type(4)));
typedef float f32x4 __attribute__((ext_vector_type(4)));
#define MFMA16(a, b, c) __builtin_amdgcn_mfma_f32_16x16x32_bf16(a, b, c, 0, 0, 0)

__device__ __forceinline__ short f2b(float f) {
    unsigned u = __builtin_bit_cast(unsigned, f);
    unsigned r = (u + 0x7fffu + ((u >> 16) & 1u)) >> 16;
    return (short)r;
}
__device__ __forceinline__ float b2f(short s) {
    unsigned u = ((unsigned)(unsigned short)s) << 16;
    return __builtin_bit_cast(float, u);
}

// ---------------- sort-by-part kernels ----------------

__global__ __launch_bounds__(256) void hist_k(const int* __restrict__ part,
                                              int* __restrict__ counts, int n) {
    __shared__ int s_c[P_N];
    if (threadIdx.x < P_N) s_c[threadIdx.x] = 0;
    __syncthreads();
    int g = blockIdx.x * 256 + threadIdx.x;
    if (g < n) atomicAdd(&s_c[part[g]], 1);
    __syncthreads();
    if (threadIdx.x < P_N) atomicAdd(&counts[threadIdx.x], s_c[threadIdx.x]);
}

__global__ void offs_k(const int* __restrict__ counts, int* __restrict__ offs) {
    if (threadIdx.x == 0) {
        int o = 0;
        for (int p = 0; p < P_N; ++p) {
            offs[p] = o;
            o += (counts[p] + 127) & ~127;   // pad each part segment to 128
        }
        offs[P_N] = o;
    }
}

__global__ __launch_bounds__(256) void scatter_k(const int* __restrict__ part,
                                                 const int* __restrict__ offs,
                                                 int* __restrict__ cursors,
                                                 int* __restrict__ perm, int n) {
    const int t = threadIdx.x;
    const int g = blockIdx.x * 256 + t;
    const int p = (g < n) ? part[g] : -1;
    const int lane = t & 63;
    const int wid = t >> 6;
    __shared__ int s_wc[4][P_N];
    __shared__ int s_base[P_N];
    const unsigned long long lmask = (1ull << lane) - 1ull;
    int myrank = 0;
    for (int pp = 0; pp < P_N; ++pp) {
        unsigned long long m = __ballot(p == pp);
        if (p == pp) myrank = __popcll(m & lmask);
        if (lane == 0) s_wc[wid][pp] = __popcll(m);
    }
    __syncthreads();
    if (t < P_N) {
        int tot = s_wc[0][t] + s_wc[1][t] + s_wc[2][t] + s_wc[3][t];
        s_base[t] = atomicAdd(&cursors[t], tot);
    }
    __syncthreads();
    if (g < n) {
        int pre = 0;
        #pragma unroll
        for (int w2 = 0; w2 < 4; ++w2) if (w2 < wid) pre += s_wc[w2][p];
        perm[offs[p] + s_base[p] + pre + myrank] = g;
    }
}

// ---------------- merged weight prep (1 launch) ----------------

__device__ __forceinline__ float mseg(int l, const float* __restrict__ src,
                                      int DIN, int DOUT, int NP, int pps) {
    const int pn = NP * 128;
    const int p = l / pn;
    const int r = l - p * pn;
    const int n = r >> 7, k = r & 127;
    return (n < DOUT && k < DIN) ? src[p * pps + k * DOUT + n] : 0.f;
}
__device__ __forceinline__ float cseg(int l, const float* __restrict__ src, int CIN) {
    const int per = 9 * 64 * CIN;
    const int ll = l / per;
    int rem = l - ll * per;
    const int tap = rem / (64 * CIN);
    rem -= tap * 64 * CIN;
    const int och = rem / CIN;
    const int ci = rem - och * CIN;
    return src[((ll * 64 + och) * CIN + ci) * 9 + tap];
}

__global__ __launch_bounds__(256) void prep_k(
        const float* __restrict__ m1wi, const float* __restrict__ m1wh,
        const float* __restrict__ m1wo, const float* __restrict__ m2wi,
        const float* __restrict__ m2wh, const float* __restrict__ m2wo,
        const float* __restrict__ cinw, const float* __restrict__ chw,
        short* __restrict__ wb) {
    const int idx = blockIdx.x * 256 + threadIdx.x;
    if (idx >= 651264) return;
    float v;
    if      (idx < 81920)  v = mseg(idx,          m1wi,         96, 128, 128, 12288);
    else if (idx < 163840) v = mseg(idx - 81920,  m1wh,        128, 128, 128, 32768);
    else if (idx < 245760) v = mseg(idx - 163840, m1wh + 16384,128, 128, 128, 32768);
    else if (idx < 256000) v = mseg(idx - 245760, m1wo,        128,  11,  16, 1408);
    else if (idx < 337920) v = mseg(idx - 256000, m2wi,        110, 128, 128, 14080);
    else if (idx < 419840) v = mseg(idx - 337920, m2wh,        128, 128, 128, 32768);
    else if (idx < 501760) v = mseg(idx - 419840, m2wh + 16384,128, 128, 128, 32768);
    else if (idx < 522240) v = mseg(idx - 501760, m2wo,        128,  32,  32, 4096);
    else if (idx < 540672) v = cseg(idx - 522240, cinw, 32);
    else                   v = cseg(idx - 540672, chw, 64);
    wb[idx] = f2b(v);
}

// ---------------- fused MLP1+MLP2 (bf16 MFMA) ----------------

template<int NKC, bool ACT>
__device__ __forceinline__ void dlayerSep(const short* __restrict__ wt,
                                          const float* __restrict__ bias,
                                          const short* src, short* dst, int m0, int n0) {
    const int lane = threadIdx.x & 63;
    const int ln = lane & 15, lq = lane >> 4;
    short8 B[4][NKC];
    float bs[4];
    #pragma unroll
    for (int nt = 0; nt < 4; ++nt) {
        #pragma unroll
        for (int kc = 0; kc < NKC; ++kc)
            B[nt][kc] = *(const short8*)(wt + (n0 + nt * 16 + ln) * 128 + kc * 32 + lq * 8);
        bs[nt] = bias[n0 + nt * 16 + ln];
    }
    #pragma unroll
    for (int mt = 0; mt < 4; ++mt) {
        short8 A[NKC];
        #pragma unroll
        for (int kc = 0; kc < NKC; ++kc)
            A[kc] = *(const short8*)(src + (m0 + mt * 16 + ln) * XP + kc * 32 + lq * 8);
        #pragma unroll
        for (int nt = 0; nt < 4; ++nt) {
            f32x4 acc = {bs[nt], bs[nt], bs[nt], bs[nt]};
            #pragma unroll
            for (int kc = 0; kc < NKC; ++kc)
                acc = MFMA16(A[kc], B[nt][kc], acc);
            #pragma unroll
            for (int r = 0; r < 4; ++r) {
                float v = acc[r];
                if (ACT) v = fmaxf(v, 0.01f * v);
                dst[(m0 + mt * 16 + lq * 4 + r) * XP + n0 + nt * 16 + ln] = f2b(v);
            }
        }
    }
}

template<bool ACT>
__device__ __forceinline__ void dlayerIP(const short* __restrict__ wt,
                                         const float* __restrict__ bias,
                                         short* buf, int m0, int n0) {
    const int lane = threadIdx.x & 63;
    const int ln = lane & 15, lq = lane >> 4;
    short8 A[4][4];
    #pragma unroll
    for (int mt = 0; mt < 4; ++mt)
        #pragma unroll
        for (int kc = 0; kc < 4; ++kc)
            A[mt][kc] = *(const short8*)(buf + (m0 + mt * 16 + ln) * XP + kc * 32 + lq * 8);
    __syncthreads();
    #pragma unroll
    for (int nt = 0; nt < 4; ++nt) {
        short8 B[4];
        #pragma unroll
        for (int kc = 0; kc < 4; ++kc)
            B[kc] = *(const short8*)(wt + (n0 + nt * 16 + ln) * 128 + kc * 32 + lq * 8);
        const float bs = bias[n0 + nt * 16 + ln];
        #pragma unroll
        for (int mt = 0; mt < 4; ++mt) {
            f32x4 acc = {bs, bs, bs, bs};
            #pragma unroll
            for (int kc = 0; kc < 4; ++kc)
                acc = MFMA16(A[mt][kc], B[kc], acc);
            #pragma unroll
            for (int r = 0; r < 4; ++r) {
                float v = acc[r];
                if (ACT) v = fmaxf(v, 0.01f * v);
                buf[(m0 + mt * 16 + lq * 4 + r) * XP + n0 + nt * 16 + ln] = f2b(v);
            }
        }
    }
    __syncthreads();
}

__global__ __launch_bounds__(256) void mlp_k(
        const float* __restrict__ latent_z, const float* __restrict__ latent_f,
        const float* __restrict__ cano,
        const short* __restrict__ wt1i, const float* __restrict__ b1i,
        const short* __restrict__ wt1h0, const short* __restrict__ wt1h1,
        const float* __restrict__ b1h,
        const short* __restrict__ wt1o, const float* __restrict__ b1o,
        const short* __restrict__ wt2i, const float* __restrict__ b2i,
        const short* __restrict__ wt2h0, const short* __restrict__ wt2h1,
        const float* __restrict__ b2h,
        const short* __restrict__ wt2o, const float* __restrict__ b2o,
        const int* __restrict__ uv_idx, const int* __restrict__ perm,
        const int* __restrict__ offs, const int* __restrict__ counts,
        unsigned short* __restrict__ uvmap /* [PIX][32] bf16 */) {
    __shared__ short s_x[128 * XP];
    __shared__ short s_h[128 * XP];
    __shared__ int s_g[128];
    __shared__ int s_uv[128];

    const int t = threadIdx.x;
    const int lane = t & 63;
    const int w = t >> 6;
    const int ln = lane & 15, lq = lane >> 4;
    const int pos0 = blockIdx.x * 128;
    if (pos0 >= offs[P_N]) return;
    int p = 0;
    #pragma unroll
    for (int q = 1; q < P_N; ++q) if (pos0 >= offs[q]) p = q;
    const int vend = offs[p] + counts[p];

    if (t < 128) {
        const int pos = pos0 + t;
        const int g = (pos < vend) ? perm[pos] : -1;
        s_g[t] = g;
        s_uv[t] = (g >= 0) ? uv_idx[g] : 0;
    }
    __syncthreads();

    for (int i = t; i < 128 * 16; i += 256) {   // latent_f, float4
        const int g = i >> 4, k4 = (i & 15) * 4;
        const float4 v = *(const float4*)(latent_f + p * 64 + k4);
        short4v o = {f2b(v.x), f2b(v.y), f2b(v.z), f2b(v.w)};
        *(short4v*)(s_x + g * XP + k4) = o;
    }
    for (int i = t; i < 128 * 8; i += 256) {    // latent_z, float4
        const int g = i >> 3, k4 = (i & 7) * 4;
        const int gg = s_g[g];
        short4v o = {0, 0, 0, 0};
        if (gg >= 0) {
            const float4 v = *(const float4*)(latent_z + gg * 32 + k4);
            o[0] = f2b(v.x); o[1] = f2b(v.y); o[2] = f2b(v.z); o[3] = f2b(v.w);
        }
        *(short4v*)(s_x + g * XP + 64 + k4) = o;
    }
    for (int i = t; i < 128 * 3; i += 256) {
        const int g = i / 3, k = i - g * 3;
        const int gg = s_g[g];
        s_x[g * XP + 96 + k] = (gg >= 0) ? f2b(cano[gg * 3 + k]) : 0;
    }
    for (int i = t; i < 128 * 37; i += 256) {
        const int g = i / 37, k = 99 + (i - g * 37);
        s_x[g * XP + k] = 0;
    }
    __syncthreads();

    const int m0 = (w >> 1) * 64, n0 = (w & 1) * 64;

    // MLP1: 96 -> 128 -> 128 -> 128 -> 11
    dlayerSep<3, true>(wt1i + p * 16384, b1i + p * 128, s_x, s_h, m0, n0);
    __syncthreads();
    dlayerIP<true>(wt1h0 + p * 16384, b1h + (p * 2 + 0) * 128, s_h, m0, n0);
    dlayerIP<true>(wt1h1 + p * 16384, b1h + (p * 2 + 1) * 128, s_h, m0, n0);
    if ((w & 1) == 0) {
        short8 B[4];
        #pragma unroll
        for (int kc = 0; kc < 4; ++kc)
            B[kc] = *(const short8*)(wt1o + p * 2048 + ln * 128 + kc * 32 + lq * 8);
        const float bs = (ln < 11) ? b1o[p * 11 + ln] : 0.f;
        #pragma unroll
        for (int mt = 0; mt < 4; ++mt) {
            short8 A[4];
            #pragma unroll
            for (int kc = 0; kc < 4; ++kc)
                A[kc] = *(const short8*)(s_h + (m0 + mt * 16 + ln) * XP + kc * 32 + lq * 8);
            f32x4 acc = {bs, bs, bs, bs};
            #pragma unroll
            for (int kc = 0; kc < 4; ++kc) acc = MFMA16(A[kc], B[kc], acc);
            if (ln < 11) {
                #pragma unroll
                for (int r = 0; r < 4; ++r)
                    s_x[(m0 + mt * 16 + lq * 4 + r) * XP + 99 + ln] = f2b(acc[r]);
            }
        }
    }
    __syncthreads();

    // MLP2: 110(pad 128) -> 128 -> 128 -> 128 -> 32
    dlayerSep<4, true>(wt2i + p * 16384, b2i + p * 128, s_x, s_h, m0, n0);
    __syncthreads();
    dlayerIP<true>(wt2h0 + p * 16384, b2h + (p * 2 + 0) * 128, s_h, m0, n0);
    dlayerIP<true>(wt2h1 + p * 16384, b2h + (p * 2 + 1) * 128, s_h, m0, n0);
    {
        const int nt0 = (w & 1) * 16;
        short8 B[4];
        #pragma unroll
        for (int kc = 0; kc < 4; ++kc)
            B[kc] = *(const short8*)(wt2o + p * 4096 + (nt0 + ln) * 128 + kc * 32 + lq * 8);
        const float bs = b2o[p * 32 + nt0 + ln];
        #pragma unroll
        for (int mt = 0; mt < 4; ++mt) {
            short8 A[4];
            #pragma unroll
            for (int kc = 0; kc < 4; ++kc)
                A[kc] = *(const short8*)(s_h + (m0 + mt * 16 + ln) * XP + kc * 32 + lq * 8);
            f32x4 acc = {bs, bs, bs, bs};
            #pragma unroll
            for (int kc = 0; kc < 4; ++kc) acc = MFMA16(A[kc], B[kc], acc);
            #pragma unroll
            for (int r = 0; r < 4; ++r) {
                const int m = m0 + mt * 16 + lq * 4 + r;
                const int g = s_g[m];
                if (g >= 0)
                    uvmap[s_uv[m] * 32 + nt0 + ln] = (unsigned short)f2b(acc[r]);
            }
        }
    }
}

// ---------------- CNN (bf16 MFMA implicit GEMM, tap-decomposed) ----------------
// block = 512 threads (8 waves), 16x16 pixel tile, 64 och.
// Wave w (0..7): pixel rows 2w, 2w+1 x 64 och (acc[2][4]).
// Weights per-tap from GLOBAL (L2-resident) into registers -> single barrier.
// TRANS: 0 raw, 1 relu, 2 IN+relu (mean/rstd from prev-layer ssum/ssq)

template<int CIN, int TRANS, bool STATS>
__global__ __launch_bounds__(512) void conv_k(
        const unsigned short* __restrict__ in,   // [PIX][CIN] bf16
        const short* __restrict__ wt,            // [9][64][CIN] bf16
        const float* __restrict__ bias,
        const float* __restrict__ psum, const float* __restrict__ psq,
        unsigned short* __restrict__ out,        // [PIX][64] bf16
        float* __restrict__ ssum, float* __restrict__ ssq) {
    constexpr int CS = CIN + 8;
    __shared__ short s_in[18 * 18 * CS];
    __shared__ float s_mr[2][64];

    const int t = threadIdx.x;
    const int lane = t & 63;
    const int ln = lane & 15, lq = lane >> 4;
    const int tx0 = blockIdx.x * 16, ty0 = blockIdx.y * 16;

    if (TRANS == 2 && t < 64) {
        const float m = psum[t] * (1.f / PIX);
        const float vv = psq[t] * (1.f / PIX) - m * m;
        s_mr[0][t] = m;
        s_mr[1][t] = rsqrtf(vv + 1e-5f);
    }
    if (TRANS == 2) __syncthreads();

    constexpr int RUNS = CIN / 8;
    for (int i = t; i < 324 * RUNS; i += 512) {
        const int sp = i / RUNS, run = i - sp * RUNS;
        const int r = sp / 18, c = sp - r * 18;
        const int gy = ty0 + r - 1, gx = tx0 + c - 1;
        short* dst = &s_in[(r * 18 + c) * CS + run * 8];
        if (gy >= 0 && gy < 256 && gx >= 0 && gx < 256) {
            short8 v = *(const short8*)(in + ((gy * 256 + gx) * CIN + run * 8));
            if (TRANS == 0) {
                *(short8*)dst = v;
            } else {
                short8 o;
                #pragma unroll
                for (int j = 0; j < 8; ++j) {
                    float f = b2f(v[j]);
                    if (TRANS == 2) f = (f - s_mr[0][run * 8 + j]) * s_mr[1][run * 8 + j];
                    o[j] = f2b(fmaxf(f, 0.f));
                }
                *(short8*)dst = o;
            }
        } else {
            short8 z = {0, 0, 0, 0, 0, 0, 0, 0};
            *(short8*)dst = z;
        }
    }
    __syncthreads();   // the ONLY barrier — waves free-run from here

    f32x4 acc[2][4];
    {
        float bs[4];
        #pragma unroll
        for (int nt = 0; nt < 4; ++nt) bs[nt] = bias[nt * 16 + ln];
        #pragma unroll
        for (int mt = 0; mt < 2; ++mt)
            #pragma unroll
            for (int nt = 0; nt < 4; ++nt) {
                f32x4 a = {bs[nt], bs[nt], bs[nt], bs[nt]};
                acc[mt][nt] = a;
            }
    }

    const int r0 = (t >> 6) * 2;
    #pragma unroll 3
    for (int tap = 0; tap < 9; ++tap) {
        const int dy = tap / 3, dx = tap % 3;
        const short* wtap = wt + tap * 64 * CIN;
        short8 B[CIN / 32][4];
        #pragma unroll
        for (int kc = 0; kc < CIN / 32; ++kc)
            #pragma unroll
            for (int nt = 0; nt < 4; ++nt)
                B[kc][nt] = *(const short8*)(wtap + (nt * 16 + ln) * CIN + kc * 32 + lq * 8);
        #pragma unroll
        for (int kc = 0; kc < CIN / 32; ++kc) {
            short8 A[2];
            #pragma unroll
            for (int mt = 0; mt < 2; ++mt)
                A[mt] = *(const short8*)&s_in[((r0 + mt + dy) * 18 + ln + dx) * CS + kc * 32 + lq * 8];
            #pragma unroll
            for (int mt = 0; mt < 2; ++mt)
                #pragma unroll
                for (int nt = 0; nt < 4; ++nt)
                    acc[mt][nt] = MFMA16(A[mt], B[kc][nt], acc[mt][nt]);
        }
    }

    #pragma unroll
    for (int nt = 0; nt < 4; ++nt) {
        float lsum = 0.f, lsqs = 0.f;
        #pragma unroll
        for (int mt = 0; mt < 2; ++mt) {
            const int gy = ty0 + r0 + mt;
            #pragma unroll
            for (int r = 0; r < 4; ++r) {
                const float v = acc[mt][nt][r];
                const int gx = tx0 + lq * 4 + r;
                out[(gy * 256 + gx) * 64 + nt * 16 + ln] = (unsigned short)f2b(v);
                if (STATS) { lsum += v; lsqs = fmaf(v, v, lsqs); }
            }
        }
        if (STATS) {
            lsum += __shfl_xor(lsum, 16, 64);
            lsum += __shfl_xor(lsum, 32, 64);
            lsqs += __shfl_xor(lsqs, 16, 64);
            lsqs += __shfl_xor(lsqs, 32, 64);
            if (lq == 0) {
                atomicAdd(&ssum[nt * 16 + ln], lsum);
                atomicAdd(&ssq[nt * 16 + ln], lsqs);
            }
        }
    }
}

// conv_out: 3 och + sigmoid, input = IN (no relu), fp32 VALU, output CHW fp32
__global__ __launch_bounds__(256) void convout_k(
        const unsigned short* __restrict__ in,   // [PIX][64] bf16
        const float* __restrict__ w,             // cow [3][64][3][3]
        const float* __restrict__ bias,
        const float* __restrict__ psum, const float* __restrict__ psq,
        float* __restrict__ out) {
    constexpr int CS = 72;
    __shared__ short s_in[18 * 18 * CS];
    __shared__ float s_w[3][9][64];
    __shared__ float s_mr[2][64];

    const int t = threadIdx.x;
    const int tx0 = blockIdx.x * 16, ty0 = blockIdx.y * 16;
    if (t < 64) {
        const float m = psum[t] * (1.f / PIX);
        const float vv = psq[t] * (1.f / PIX) - m * m;
        s_mr[0][t] = m;
        s_mr[1][t] = rsqrtf(vv + 1e-5f);
    }
    __syncthreads();

    for (int i = t; i < 324 * 8; i += 256) {
        const int sp = i >> 3, run = i & 7;
        const int r = sp / 18, c = sp - r * 18;
        const int gy = ty0 + r - 1, gx = tx0 + c - 1;
        short* dst = &s_in[(r * 18 + c) * CS + run * 8];
        if (gy >= 0 && gy < 256 && gx >= 0 && gx < 256) {
            short8 v = *(const short8*)(in + ((gy * 256 + gx) * 64 + run * 8));
            short8 o;
            #pragma unroll
            for (int j = 0; j < 8; ++j) {
                const float f = (b2f(v[j]) - s_mr[0][run * 8 + j]) * s_mr[1][run * 8 + j];
                o[j] = f2b(f);
            }
            *(short8*)dst = o;
        } else {
            short8 z = {0, 0, 0, 0, 0, 0, 0, 0};
            *(short8*)dst = z;
        }
    }
    for (int i = t; i < 1728; i += 256) {
        const int o = i / 576;
        const int rem = i - o * 576;
        const int tap = rem >> 6;
        const int ci = rem & 63;
        s_w[o][tap][ci] = w[o * 576 + ci * 9 + tap];
    }
    __syncthreads();

    const int py = t >> 4, px = t & 15;
    float a0 = bias[0], a1 = bias[1], a2 = bias[2];
    for (int tap = 0; tap < 9; ++tap) {
        const int dy = tap / 3, dx = tap % 3;
        const short* rp = &s_in[((py + dy) * 18 + (px + dx)) * CS];
        #pragma unroll
        for (int c8 = 0; c8 < 8; ++c8) {
            short8 v = *(const short8*)(rp + c8 * 8);
            #pragma unroll
            for (int j = 0; j < 8; ++j) {
                const float f = b2f(v[j]);
                const int ci = c8 * 8 + j;
                a0 = fmaf(f, s_w[0][tap][ci], a0);
                a1 = fmaf(f, s_w[1][tap][ci], a1);
                a2 = fmaf(f, s_w[2][tap][ci], a2);
            }
        }
    }
    const int pix = (ty0 + py) * 256 + tx0 + px;
    out[pix]           = 1.f / (1.f + expf(-a0));
    out[PIX + pix]     = 1.f / (1.f + expf(-a1));
    out[2 * PIX + pix] = 1.f / (1.f + expf(-a2));
}

// ---------------- launch ----------------

extern "C" void kernel_launch(void* const* d_in, const int* in_sizes, int n_in,
                              void* d_out, int out_size, void* d_ws, size_t ws_size,
                              hipStream_t stream) {
    (void)in_sizes; (void)n_in; (void)out_size; (void)ws_size;
    const float* latent_z = (const float*)d_in[0];
    const float* latent_f = (const float*)d_in[1];
    const float* cano     = (const float*)d_in[2];
    const float* m1wi = (const float*)d_in[3];
    const float* m1bi = (const float*)d_in[4];
    const float* m1wh = (const float*)d_in[5];
    const float* m1bh = (const float*)d_in[6];
    const float* m1wo = (const float*)d_in[7];
    const float* m1bo = (const float*)d_in[8];
    const float* m2wi = (const float*)d_in[9];
    const float* m2bi = (const float*)d_in[10];
    const float* m2wh = (const float*)d_in[11];
    const float* m2bh = (const float*)d_in[12];
    const float* m2wo = (const float*)d_in[13];
    const float* m2bo = (const float*)d_in[14];
    const float* cinw = (const float*)d_in[15];
    const float* cinb = (const float*)d_in[16];
    const float* chw  = (const float*)d_in[17];
    const float* chb  = (const float*)d_in[18];
    const float* cow  = (const float*)d_in[19];
    const float* cob  = (const float*)d_in[20];
    const int* gs_part = (const int*)d_in[21];
    const int* uv_idx  = (const int*)d_in[22];

    float* ws = (float*)d_ws;
    unsigned short* actA = (unsigned short*)ws;                 // [PIX][64] bf16 = 8 MB
    unsigned short* actB = (unsigned short*)(ws + 2097152);     // [PIX][64] bf16 = 8 MB
    unsigned short* uvmap = actB;                               // [PIX][32] aliases actB head

    short* wb = (short*)(ws + 4194304);
    short* wt1i  = wb;                  // 81920
    short* wt1h0 = wb + 81920;
    short* wt1h1 = wb + 163840;
    short* wt1o  = wb + 245760;         // 10240
    short* wt2i  = wb + 256000;
    short* wt2h0 = wb + 337920;
    short* wt2h1 = wb + 419840;
    short* wt2o  = wb + 501760;         // 20480
    short* cwt_in  = wb + 522240;       // 18432
    short* cwt_hid = wb + 540672;       // 110592 (end 651264 shorts)

    float* small = ws + 4194304 + 330000;
    int* counts  = (int*)small;             // 8
    int* cursors = counts + 8;              // 8
    int* offs    = cursors + 8;             // 8
    float* ssum  = small + 32;              // 3*64
    float* ssq   = ssum + 192;
    int* perm    = (int*)(ssq + 192);       // up to 40704

    hipMemsetAsync(uvmap, 0, (size_t)PIX * 32 * sizeof(unsigned short), stream);
    hipMemsetAsync(small, 0, 1024 * sizeof(float), stream);

    hist_k<<<157, 256, 0, stream>>>(gs_part, counts, G_N);
    offs_k<<<1, 64, 0, stream>>>(counts, offs);
    scatter_k<<<157, 256, 0, stream>>>(gs_part, offs, cursors, perm, G_N);

    prep_k<<<2544, 256, 0, stream>>>(m1wi, m1wh, m1wo, m2wi, m2wh, m2wo, cinw, chw, wb);

    mlp_k<<<318, 256, 0, stream>>>(latent_z, latent_f, cano,
        wt1i, m1bi, wt1h0, wt1h1, m1bh, wt1o, m1bo,
        wt2i, m2bi, wt2h0, wt2h1, m2bh, wt2o, m2bo,
        uv_idx, perm, offs, counts, uvmap);

    dim3 cgrid(16, 16);
    // conv_in: uvmap(raw) -> actA
    conv_k<32, 0, false><<<cgrid, 512, 0, stream>>>(uvmap, cwt_in, cinb,
        nullptr, nullptr, actA, nullptr, nullptr);
    // hidden 0: relu(actA) -> actB, stats slot0
    conv_k<64, 1, true><<<cgrid, 512, 0, stream>>>(actA, cwt_hid, chb,
        nullptr, nullptr, actB, ssum, ssq);
    // hidden 1: relu(IN(actB)) -> actA, stats slot1
    conv_k<64, 2, true><<<cgrid, 512, 0, stream>>>(actB, cwt_hid + 36864, chb + 64,
        ssum, ssq, actA, ssum + 64, ssq + 64);
    // hidden 2: relu(IN(actA)) -> actB, stats slot2
    conv_k<64, 2, true><<<cgrid, 512, 0, stream>>>(actA, cwt_hid + 73728, chb + 128,
        ssum + 64, ssq + 64, actB, ssum + 128, ssq + 128);
    // conv_out: IN(actB) -> sigmoid -> d_out (CHW fp32)
    convout_k<<<cgrid, 256, 0, stream>>>(actB, cow, cob,
        ssum + 128, ssq + 128, (float*)d_out);
}

// Round 6
// 292.228 us; speedup vs baseline: 1.3024x; 1.3024x over previous
//
#include <hip/hip_runtime.h>

#define G_N 40000
#define P_N 5
#define PIX 65536   // 256*256
#define XP 136      // MLP LDS activation row stride (shorts)

typedef short short8 __attribute__((ext_vector_type(8)));
typedef short short4v __attribute__((ext_vector_type(4)));
typedef float f32x4 __attribute__((ext_vector_type(4)));
#define MFMA16(a, b, c) __builtin_amdgcn_mfma_f32_16x16x32_bf16(a, b, c, 0, 0, 0)

__device__ __forceinline__ short f2b(float f) {
    unsigned u = __builtin_bit_cast(unsigned, f);
    unsigned r = (u + 0x7fffu + ((u >> 16) & 1u)) >> 16;
    return (short)r;
}
__device__ __forceinline__ float b2f(short s) {
    unsigned u = ((unsigned)(unsigned short)s) << 16;
    return __builtin_bit_cast(float, u);
}

// ---------------- sort-by-part kernels ----------------

__global__ __launch_bounds__(256) void hist_k(const int* __restrict__ part,
                                              int* __restrict__ counts, int n) {
    __shared__ int s_c[P_N];
    if (threadIdx.x < P_N) s_c[threadIdx.x] = 0;
    __syncthreads();
    int g = blockIdx.x * 256 + threadIdx.x;
    if (g < n) atomicAdd(&s_c[part[g]], 1);
    __syncthreads();
    if (threadIdx.x < P_N) atomicAdd(&counts[threadIdx.x], s_c[threadIdx.x]);
}

__global__ void offs_k(const int* __restrict__ counts, int* __restrict__ offs) {
    if (threadIdx.x == 0) {
        int o = 0;
        for (int p = 0; p < P_N; ++p) {
            offs[p] = o;
            o += (counts[p] + 127) & ~127;   // pad each part segment to 128
        }
        offs[P_N] = o;
    }
}

__global__ __launch_bounds__(256) void scatter_k(const int* __restrict__ part,
                                                 const int* __restrict__ offs,
                                                 int* __restrict__ cursors,
                                                 int* __restrict__ perm, int n) {
    const int t = threadIdx.x;
    const int g = blockIdx.x * 256 + t;
    const int p = (g < n) ? part[g] : -1;
    const int lane = t & 63;
    const int wid = t >> 6;
    __shared__ int s_wc[4][P_N];
    __shared__ int s_base[P_N];
    const unsigned long long lmask = (1ull << lane) - 1ull;
    int myrank = 0;
    for (int pp = 0; pp < P_N; ++pp) {
        unsigned long long m = __ballot(p == pp);
        if (p == pp) myrank = __popcll(m & lmask);
        if (lane == 0) s_wc[wid][pp] = __popcll(m);
    }
    __syncthreads();
    if (t < P_N) {
        int tot = s_wc[0][t] + s_wc[1][t] + s_wc[2][t] + s_wc[3][t];
        s_base[t] = atomicAdd(&cursors[t], tot);
    }
    __syncthreads();
    if (g < n) {
        int pre = 0;
        #pragma unroll
        for (int w2 = 0; w2 < 4; ++w2) if (w2 < wid) pre += s_wc[w2][p];
        perm[offs[p] + s_base[p] + pre + myrank] = g;
    }
}

// ---------------- merged weight prep (1 launch) ----------------

__device__ __forceinline__ float mseg(int l, const float* __restrict__ src,
                                      int DIN, int DOUT, int NP, int pps) {
    const int pn = NP * 128;
    const int p = l / pn;
    const int r = l - p * pn;
    const int n = r >> 7, k = r & 127;
    return (n < DOUT && k < DIN) ? src[p * pps + k * DOUT + n] : 0.f;
}
__device__ __forceinline__ float cseg(int l, const float* __restrict__ src, int CIN) {
    const int per = 9 * 64 * CIN;
    const int ll = l / per;
    int rem = l - ll * per;
    const int tap = rem / (64 * CIN);
    rem -= tap * 64 * CIN;
    const int och = rem / CIN;
    const int ci = rem - och * CIN;
    return src[((ll * 64 + och) * CIN + ci) * 9 + tap];
}

__global__ __launch_bounds__(256) void prep_k(
        const float* __restrict__ m1wi, const float* __restrict__ m1wh,
        const float* __restrict__ m1wo, const float* __restrict__ m2wi,
        const float* __restrict__ m2wh, const float* __restrict__ m2wo,
        const float* __restrict__ cinw, const float* __restrict__ chw,
        short* __restrict__ wb) {
    const int idx = blockIdx.x * 256 + threadIdx.x;
    if (idx >= 651264) return;
    float v;
    if      (idx < 81920)  v = mseg(idx,          m1wi,         96, 128, 128, 12288);
    else if (idx < 163840) v = mseg(idx - 81920,  m1wh,        128, 128, 128, 32768);
    else if (idx < 245760) v = mseg(idx - 163840, m1wh + 16384,128, 128, 128, 32768);
    else if (idx < 256000) v = mseg(idx - 245760, m1wo,        128,  11,  16, 1408);
    else if (idx < 337920) v = mseg(idx - 256000, m2wi,        110, 128, 128, 14080);
    else if (idx < 419840) v = mseg(idx - 337920, m2wh,        128, 128, 128, 32768);
    else if (idx < 501760) v = mseg(idx - 419840, m2wh + 16384,128, 128, 128, 32768);
    else if (idx < 522240) v = mseg(idx - 501760, m2wo,        128,  32,  32, 4096);
    else if (idx < 540672) v = cseg(idx - 522240, cinw, 32);
    else                   v = cseg(idx - 540672, chw, 64);
    wb[idx] = f2b(v);
}

// ---------------- fused MLP1+MLP2 (bf16 MFMA) ----------------

template<int NKC, bool ACT>
__device__ __forceinline__ void dlayerSep(const short* __restrict__ wt,
                                          const float* __restrict__ bias,
                                          const short* src, short* dst, int m0, int n0) {
    const int lane = threadIdx.x & 63;
    const int ln = lane & 15, lq = lane >> 4;
    short8 B[4][NKC];
    float bs[4];
    #pragma unroll
    for (int nt = 0; nt < 4; ++nt) {
        #pragma unroll
        for (int kc = 0; kc < NKC; ++kc)
            B[nt][kc] = *(const short8*)(wt + (n0 + nt * 16 + ln) * 128 + kc * 32 + lq * 8);
        bs[nt] = bias[n0 + nt * 16 + ln];
    }
    #pragma unroll
    for (int mt = 0; mt < 4; ++mt) {
        short8 A[NKC];
        #pragma unroll
        for (int kc = 0; kc < NKC; ++kc)
            A[kc] = *(const short8*)(src + (m0 + mt * 16 + ln) * XP + kc * 32 + lq * 8);
        #pragma unroll
        for (int nt = 0; nt < 4; ++nt) {
            f32x4 acc = {bs[nt], bs[nt], bs[nt], bs[nt]};
            #pragma unroll
            for (int kc = 0; kc < NKC; ++kc)
                acc = MFMA16(A[kc], B[nt][kc], acc);
            #pragma unroll
            for (int r = 0; r < 4; ++r) {
                float v = acc[r];
                if (ACT) v = fmaxf(v, 0.01f * v);
                dst[(m0 + mt * 16 + lq * 4 + r) * XP + n0 + nt * 16 + ln] = f2b(v);
            }
        }
    }
}

template<bool ACT>
__device__ __forceinline__ void dlayerIP(const short* __restrict__ wt,
                                         const float* __restrict__ bias,
                                         short* buf, int m0, int n0) {
    const int lane = threadIdx.x & 63;
    const int ln = lane & 15, lq = lane >> 4;
    short8 A[4][4];
    #pragma unroll
    for (int mt = 0; mt < 4; ++mt)
        #pragma unroll
        for (int kc = 0; kc < 4; ++kc)
            A[mt][kc] = *(const short8*)(buf + (m0 + mt * 16 + ln) * XP + kc * 32 + lq * 8);
    __syncthreads();
    #pragma unroll
    for (int nt = 0; nt < 4; ++nt) {
        short8 B[4];
        #pragma unroll
        for (int kc = 0; kc < 4; ++kc)
            B[kc] = *(const short8*)(wt + (n0 + nt * 16 + ln) * 128 + kc * 32 + lq * 8);
        const float bs = bias[n0 + nt * 16 + ln];
        #pragma unroll
        for (int mt = 0; mt < 4; ++mt) {
            f32x4 acc = {bs, bs, bs, bs};
            #pragma unroll
            for (int kc = 0; kc < 4; ++kc)
                acc = MFMA16(A[mt][kc], B[kc], acc);
            #pragma unroll
            for (int r = 0; r < 4; ++r) {
                float v = acc[r];
                if (ACT) v = fmaxf(v, 0.01f * v);
                buf[(m0 + mt * 16 + lq * 4 + r) * XP + n0 + nt * 16 + ln] = f2b(v);
            }
        }
    }
    __syncthreads();
}

__global__ __launch_bounds__(256) void mlp_k(
        const float* __restrict__ latent_z, const float* __restrict__ latent_f,
        const float* __restrict__ cano,
        const short* __restrict__ wt1i, const float* __restrict__ b1i,
        const short* __restrict__ wt1h0, const short* __restrict__ wt1h1,
        const float* __restrict__ b1h,
        const short* __restrict__ wt1o, const float* __restrict__ b1o,
        const short* __restrict__ wt2i, const float* __restrict__ b2i,
        const short* __restrict__ wt2h0, const short* __restrict__ wt2h1,
        const float* __restrict__ b2h,
        const short* __restrict__ wt2o, const float* __restrict__ b2o,
        const int* __restrict__ uv_idx, const int* __restrict__ perm,
        const int* __restrict__ offs, const int* __restrict__ counts,
        unsigned short* __restrict__ uvmap /* [PIX][32] bf16 */) {
    __shared__ short s_x[128 * XP];
    __shared__ short s_h[128 * XP];
    __shared__ int s_g[128];
    __shared__ int s_uv[128];

    const int t = threadIdx.x;
    const int lane = t & 63;
    const int w = t >> 6;
    const int ln = lane & 15, lq = lane >> 4;
    const int pos0 = blockIdx.x * 128;
    if (pos0 >= offs[P_N]) return;
    int p = 0;
    #pragma unroll
    for (int q = 1; q < P_N; ++q) if (pos0 >= offs[q]) p = q;
    const int vend = offs[p] + counts[p];

    if (t < 128) {
        const int pos = pos0 + t;
        const int g = (pos < vend) ? perm[pos] : -1;
        s_g[t] = g;
        s_uv[t] = (g >= 0) ? uv_idx[g] : 0;
    }
    __syncthreads();

    for (int i = t; i < 128 * 16; i += 256) {   // latent_f, float4
        const int g = i >> 4, k4 = (i & 15) * 4;
        const float4 v = *(const float4*)(latent_f + p * 64 + k4);
        short4v o = {f2b(v.x), f2b(v.y), f2b(v.z), f2b(v.w)};
        *(short4v*)(s_x + g * XP + k4) = o;
    }
    for (int i = t; i < 128 * 8; i += 256) {    // latent_z, float4
        const int g = i >> 3, k4 = (i & 7) * 4;
        const int gg = s_g[g];
        short4v o = {0, 0, 0, 0};
        if (gg >= 0) {
            const float4 v = *(const float4*)(latent_z + gg * 32 + k4);
            o[0] = f2b(v.x); o[1] = f2b(v.y); o[2] = f2b(v.z); o[3] = f2b(v.w);
        }
        *(short4v*)(s_x + g * XP + 64 + k4) = o;
    }
    for (int i = t; i < 128 * 3; i += 256) {
        const int g = i / 3, k = i - g * 3;
        const int gg = s_g[g];
        s_x[g * XP + 96 + k] = (gg >= 0) ? f2b(cano[gg * 3 + k]) : 0;
    }
    for (int i = t; i < 128 * 37; i += 256) {
        const int g = i / 37, k = 99 + (i - g * 37);
        s_x[g * XP + k] = 0;
    }
    __syncthreads();

    const int m0 = (w >> 1) * 64, n0 = (w & 1) * 64;

    // MLP1: 96 -> 128 -> 128 -> 128 -> 11
    dlayerSep<3, true>(wt1i + p * 16384, b1i + p * 128, s_x, s_h, m0, n0);
    __syncthreads();
    dlayerIP<true>(wt1h0 + p * 16384, b1h + (p * 2 + 0) * 128, s_h, m0, n0);
    dlayerIP<true>(wt1h1 + p * 16384, b1h + (p * 2 + 1) * 128, s_h, m0, n0);
    if ((w & 1) == 0) {
        short8 B[4];
        #pragma unroll
        for (int kc = 0; kc < 4; ++kc)
            B[kc] = *(const short8*)(wt1o + p * 2048 + ln * 128 + kc * 32 + lq * 8);
        const float bs = (ln < 11) ? b1o[p * 11 + ln] : 0.f;
        #pragma unroll
        for (int mt = 0; mt < 4; ++mt) {
            short8 A[4];
            #pragma unroll
            for (int kc = 0; kc < 4; ++kc)
                A[kc] = *(const short8*)(s_h + (m0 + mt * 16 + ln) * XP + kc * 32 + lq * 8);
            f32x4 acc = {bs, bs, bs, bs};
            #pragma unroll
            for (int kc = 0; kc < 4; ++kc) acc = MFMA16(A[kc], B[kc], acc);
            if (ln < 11) {
                #pragma unroll
                for (int r = 0; r < 4; ++r)
                    s_x[(m0 + mt * 16 + lq * 4 + r) * XP + 99 + ln] = f2b(acc[r]);
            }
        }
    }
    __syncthreads();

    // MLP2: 110(pad 128) -> 128 -> 128 -> 128 -> 32
    dlayerSep<4, true>(wt2i + p * 16384, b2i + p * 128, s_x, s_h, m0, n0);
    __syncthreads();
    dlayerIP<true>(wt2h0 + p * 16384, b2h + (p * 2 + 0) * 128, s_h, m0, n0);
    dlayerIP<true>(wt2h1 + p * 16384, b2h + (p * 2 + 1) * 128, s_h, m0, n0);
    {
        const int nt0 = (w & 1) * 16;
        short8 B[4];
        #pragma unroll
        for (int kc = 0; kc < 4; ++kc)
            B[kc] = *(const short8*)(wt2o + p * 4096 + (nt0 + ln) * 128 + kc * 32 + lq * 8);
        const float bs = b2o[p * 32 + nt0 + ln];
        #pragma unroll
        for (int mt = 0; mt < 4; ++mt) {
            short8 A[4];
            #pragma unroll
            for (int kc = 0; kc < 4; ++kc)
                A[kc] = *(const short8*)(s_h + (m0 + mt * 16 + ln) * XP + kc * 32 + lq * 8);
            f32x4 acc = {bs, bs, bs, bs};
            #pragma unroll
            for (int kc = 0; kc < 4; ++kc) acc = MFMA16(A[kc], B[kc], acc);
            #pragma unroll
            for (int r = 0; r < 4; ++r) {
                const int m = m0 + mt * 16 + lq * 4 + r;
                const int g = s_g[m];
                if (g >= 0)
                    uvmap[s_uv[m] * 32 + nt0 + ln] = (unsigned short)f2b(acc[r]);
            }
        }
    }
}

// ---------------- CNN (bf16 MFMA implicit GEMM) ----------------
// grid (16,16,2): 16x16 pixel tile x 32-och half -> 512 blocks (2 blocks/CU).
// block = 256 threads (4 waves); wave w: rows 4w..4w+3 x 32 och (acc[4][2]).
// ALL 9 taps' B-fragments preloaded into registers (36 short8 for CIN=64) —
// launch_bounds(256,2) permits 256 VGPRs so they stay resident. One barrier;
// after it only LDS reads + MFMA. TRANS: 0 raw, 1 relu, 2 IN+relu.

template<int CIN, int TRANS, bool STATS>
__global__ __launch_bounds__(256, 2) void conv_k(
        const unsigned short* __restrict__ in,   // [PIX][CIN] bf16
        const short* __restrict__ wt,            // [9][64][CIN] bf16
        const float* __restrict__ bias,
        const float* __restrict__ psum, const float* __restrict__ psq,
        unsigned short* __restrict__ out,        // [PIX][64] bf16
        float* __restrict__ ssum, float* __restrict__ ssq) {
    constexpr int CS = CIN + 8;
    constexpr int NKC = CIN / 32;
    __shared__ short s_in[18 * 18 * CS];
    __shared__ float s_mr[2][64];

    const int t = threadIdx.x;
    const int lane = t & 63;
    const int ln = lane & 15, lq = lane >> 4;
    const int tx0 = blockIdx.x * 16, ty0 = blockIdx.y * 16;
    const int och0 = blockIdx.z * 32;

    // B preload: 9 taps x NKC x 2 n-tiles, straight from global (L2-hot)
    short8 B[9][NKC][2];
    #pragma unroll
    for (int tap = 0; tap < 9; ++tap)
        #pragma unroll
        for (int kc = 0; kc < NKC; ++kc)
            #pragma unroll
            for (int nt = 0; nt < 2; ++nt)
                B[tap][kc][nt] = *(const short8*)(wt +
                    (tap * 64 + och0 + nt * 16 + ln) * CIN + kc * 32 + lq * 8);

    if (TRANS == 2 && t < 64) {
        const float m = psum[t] * (1.f / PIX);
        const float vv = psq[t] * (1.f / PIX) - m * m;
        s_mr[0][t] = m;
        s_mr[1][t] = rsqrtf(vv + 1e-5f);
    }
    if (TRANS == 2) __syncthreads();

    constexpr int RUNS = CIN / 8;
    for (int i = t; i < 324 * RUNS; i += 256) {
        const int sp = i / RUNS, run = i - sp * RUNS;
        const int r = sp / 18, c = sp - r * 18;
        const int gy = ty0 + r - 1, gx = tx0 + c - 1;
        short* dst = &s_in[(r * 18 + c) * CS + run * 8];
        if (gy >= 0 && gy < 256 && gx >= 0 && gx < 256) {
            short8 v = *(const short8*)(in + ((gy * 256 + gx) * CIN + run * 8));
            if (TRANS == 0) {
                *(short8*)dst = v;
            } else {
                short8 o;
                #pragma unroll
                for (int j = 0; j < 8; ++j) {
                    float f = b2f(v[j]);
                    if (TRANS == 2) f = (f - s_mr[0][run * 8 + j]) * s_mr[1][run * 8 + j];
                    o[j] = f2b(fmaxf(f, 0.f));
                }
                *(short8*)dst = o;
            }
        } else {
            short8 z = {0, 0, 0, 0, 0, 0, 0, 0};
            *(short8*)dst = z;
        }
    }
    __syncthreads();   // the ONLY barrier

    f32x4 acc[4][2];
    {
        float bs[2];
        #pragma unroll
        for (int nt = 0; nt < 2; ++nt) bs[nt] = bias[och0 + nt * 16 + ln];
        #pragma unroll
        for (int mt = 0; mt < 4; ++mt)
            #pragma unroll
            for (int nt = 0; nt < 2; ++nt) {
                f32x4 a = {bs[nt], bs[nt], bs[nt], bs[nt]};
                acc[mt][nt] = a;
            }
    }

    const int r0 = (t >> 6) * 4;
    #pragma unroll
    for (int tap = 0; tap < 9; ++tap) {
        const int dy = tap / 3, dx = tap - dy * 3;
        #pragma unroll
        for (int kc = 0; kc < NKC; ++kc) {
            short8 A[4];
            #pragma unroll
            for (int mt = 0; mt < 4; ++mt)
                A[mt] = *(const short8*)&s_in[((r0 + mt + dy) * 18 + ln + dx) * CS + kc * 32 + lq * 8];
            #pragma unroll
            for (int mt = 0; mt < 4; ++mt)
                #pragma unroll
                for (int nt = 0; nt < 2; ++nt)
                    acc[mt][nt] = MFMA16(A[mt], B[tap][kc][nt], acc[mt][nt]);
        }
    }

    #pragma unroll
    for (int nt = 0; nt < 2; ++nt) {
        float lsum = 0.f, lsqs = 0.f;
        #pragma unroll
        for (int mt = 0; mt < 4; ++mt) {
            const int gy = ty0 + r0 + mt;
            #pragma unroll
            for (int r = 0; r < 4; ++r) {
                const float v = acc[mt][nt][r];
                const int gx = tx0 + lq * 4 + r;
                out[(gy * 256 + gx) * 64 + och0 + nt * 16 + ln] = (unsigned short)f2b(v);
                if (STATS) { lsum += v; lsqs = fmaf(v, v, lsqs); }
            }
        }
        if (STATS) {
            lsum += __shfl_xor(lsum, 16, 64);
            lsum += __shfl_xor(lsum, 32, 64);
            lsqs += __shfl_xor(lsqs, 16, 64);
            lsqs += __shfl_xor(lsqs, 32, 64);
            if (lq == 0) {
                atomicAdd(&ssum[och0 + nt * 16 + ln], lsum);
                atomicAdd(&ssq[och0 + nt * 16 + ln], lsqs);
            }
        }
    }
}

// conv_out: 3 och + sigmoid, input = IN (no relu), fp32 VALU, output CHW fp32
__global__ __launch_bounds__(256) void convout_k(
        const unsigned short* __restrict__ in,   // [PIX][64] bf16
        const float* __restrict__ w,             // cow [3][64][3][3]
        const float* __restrict__ bias,
        const float* __restrict__ psum, const float* __restrict__ psq,
        float* __restrict__ out) {
    constexpr int CS = 72;
    __shared__ short s_in[18 * 18 * CS];
    __shared__ float s_w[3][9][64];
    __shared__ float s_mr[2][64];

    const int t = threadIdx.x;
    const int tx0 = blockIdx.x * 16, ty0 = blockIdx.y * 16;
    if (t < 64) {
        const float m = psum[t] * (1.f / PIX);
        const float vv = psq[t] * (1.f / PIX) - m * m;
        s_mr[0][t] = m;
        s_mr[1][t] = rsqrtf(vv + 1e-5f);
    }
    __syncthreads();

    for (int i = t; i < 324 * 8; i += 256) {
        const int sp = i >> 3, run = i & 7;
        const int r = sp / 18, c = sp - r * 18;
        const int gy = ty0 + r - 1, gx = tx0 + c - 1;
        short* dst = &s_in[(r * 18 + c) * CS + run * 8];
        if (gy >= 0 && gy < 256 && gx >= 0 && gx < 256) {
            short8 v = *(const short8*)(in + ((gy * 256 + gx) * 64 + run * 8));
            short8 o;
            #pragma unroll
            for (int j = 0; j < 8; ++j) {
                const float f = (b2f(v[j]) - s_mr[0][run * 8 + j]) * s_mr[1][run * 8 + j];
                o[j] = f2b(f);
            }
            *(short8*)dst = o;
        } else {
            short8 z = {0, 0, 0, 0, 0, 0, 0, 0};
            *(short8*)dst = z;
        }
    }
    for (int i = t; i < 1728; i += 256) {
        const int o = i / 576;
        const int rem = i - o * 576;
        const int tap = rem >> 6;
        const int ci = rem & 63;
        s_w[o][tap][ci] = w[o * 576 + ci * 9 + tap];
    }
    __syncthreads();

    const int py = t >> 4, px = t & 15;
    float a0 = bias[0], a1 = bias[1], a2 = bias[2];
    for (int tap = 0; tap < 9; ++tap) {
        const int dy = tap / 3, dx = tap % 3;
        const short* rp = &s_in[((py + dy) * 18 + (px + dx)) * CS];
        #pragma unroll
        for (int c8 = 0; c8 < 8; ++c8) {
            short8 v = *(const short8*)(rp + c8 * 8);
            #pragma unroll
            for (int j = 0; j < 8; ++j) {
                const float f = b2f(v[j]);
                const int ci = c8 * 8 + j;
                a0 = fmaf(f, s_w[0][tap][ci], a0);
                a1 = fmaf(f, s_w[1][tap][ci], a1);
                a2 = fmaf(f, s_w[2][tap][ci], a2);
            }
        }
    }
    const int pix = (ty0 + py) * 256 + tx0 + px;
    out[pix]           = 1.f / (1.f + expf(-a0));
    out[PIX + pix]     = 1.f / (1.f + expf(-a1));
    out[2 * PIX + pix] = 1.f / (1.f + expf(-a2));
}

// ---------------- launch ----------------

extern "C" void kernel_launch(void* const* d_in, const int* in_sizes, int n_in,
                              void* d_out, int out_size, void* d_ws, size_t ws_size,
                              hipStream_t stream) {
    (void)in_sizes; (void)n_in; (void)out_size; (void)ws_size;
    const float* latent_z = (const float*)d_in[0];
    const float* latent_f = (const float*)d_in[1];
    const float* cano     = (const float*)d_in[2];
    const float* m1wi = (const float*)d_in[3];
    const float* m1bi = (const float*)d_in[4];
    const float* m1wh = (const float*)d_in[5];
    const float* m1bh = (const float*)d_in[6];
    const float* m1wo = (const float*)d_in[7];
    const float* m1bo = (const float*)d_in[8];
    const float* m2wi = (const float*)d_in[9];
    const float* m2bi = (const float*)d_in[10];
    const float* m2wh = (const float*)d_in[11];
    const float* m2bh = (const float*)d_in[12];
    const float* m2wo = (const float*)d_in[13];
    const float* m2bo = (const float*)d_in[14];
    const float* cinw = (const float*)d_in[15];
    const float* cinb = (const float*)d_in[16];
    const float* chw  = (const float*)d_in[17];
    const float* chb  = (const float*)d_in[18];
    const float* cow  = (const float*)d_in[19];
    const float* cob  = (const float*)d_in[20];
    const int* gs_part = (const int*)d_in[21];
    const int* uv_idx  = (const int*)d_in[22];

    float* ws = (float*)d_ws;
    unsigned short* actA = (unsigned short*)ws;                 // [PIX][64] bf16 = 8 MB
    unsigned short* actB = (unsigned short*)(ws + 2097152);     // [PIX][64] bf16 = 8 MB
    unsigned short* uvmap = actB;                               // [PIX][32] aliases actB head

    short* wb = (short*)(ws + 4194304);
    short* wt1i  = wb;                  // 81920
    short* wt1h0 = wb + 81920;
    short* wt1h1 = wb + 163840;
    short* wt1o  = wb + 245760;         // 10240
    short* wt2i  = wb + 256000;
    short* wt2h0 = wb + 337920;
    short* wt2h1 = wb + 419840;
    short* wt2o  = wb + 501760;         // 20480
    short* cwt_in  = wb + 522240;       // 18432
    short* cwt_hid = wb + 540672;       // 110592 (end 651264 shorts)

    float* small = ws + 4194304 + 330000;
    int* counts  = (int*)small;             // 8
    int* cursors = counts + 8;              // 8
    int* offs    = cursors + 8;             // 8
    float* ssum  = small + 32;              // 3*64
    float* ssq   = ssum + 192;
    int* perm    = (int*)(ssq + 192);       // up to 40704

    hipMemsetAsync(uvmap, 0, (size_t)PIX * 32 * sizeof(unsigned short), stream);
    hipMemsetAsync(small, 0, 1024 * sizeof(float), stream);

    hist_k<<<157, 256, 0, stream>>>(gs_part, counts, G_N);
    offs_k<<<1, 64, 0, stream>>>(counts, offs);
    scatter_k<<<157, 256, 0, stream>>>(gs_part, offs, cursors, perm, G_N);

    prep_k<<<2544, 256, 0, stream>>>(m1wi, m1wh, m1wo, m2wi, m2wh, m2wo, cinw, chw, wb);

    mlp_k<<<318, 256, 0, stream>>>(latent_z, latent_f, cano,
        wt1i, m1bi, wt1h0, wt1h1, m1bh, wt1o, m1bo,
        wt2i, m2bi, wt2h0, wt2h1, m2bh, wt2o, m2bo,
        uv_idx, perm, offs, counts, uvmap);

    dim3 cgrid(16, 16, 2);
    // conv_in: uvmap(raw) -> actA
    conv_k<32, 0, false><<<cgrid, 256, 0, stream>>>(uvmap, cwt_in, cinb,
        nullptr, nullptr, actA, nullptr, nullptr);
    // hidden 0: relu(actA) -> actB, stats slot0
    conv_k<64, 1, true><<<cgrid, 256, 0, stream>>>(actA, cwt_hid, chb,
        nullptr, nullptr, actB, ssum, ssq);
    // hidden 1: relu(IN(actB)) -> actA, stats slot1
    conv_k<64, 2, true><<<cgrid, 256, 0, stream>>>(actB, cwt_hid + 36864, chb + 64,
        ssum, ssq, actA, ssum + 64, ssq + 64);
    // hidden 2: relu(IN(actA)) -> actB, stats slot2
    conv_k<64, 2, true><<<cgrid, 256, 0, stream>>>(actA, cwt_hid + 73728, chb + 128,
        ssum + 64, ssq + 64, actB, ssum + 128, ssq + 128);
    // conv_out: IN(actB) -> sigmoid -> d_out (CHW fp32)
    convout_k<<<dim3(16, 16), 256, 0, stream>>>(actB, cow, cob,
        ssum + 128, ssq + 128, (float*)d_out);
}

// Round 7
// 262.817 us; speedup vs baseline: 1.4481x; 1.1119x over previous
//
#include <hip/hip_runtime.h>

#define G_N 40000
#define P_N 5
#define PIX 65536   // 256*256
#define XP 136      // MLP LDS activation row stride (shorts): 272 B, 16B-aligned
#define SP 40       // MLP side-tile stride (shorts): 80 B, 16B-aligned

typedef short short8 __attribute__((ext_vector_type(8)));
typedef short short4v __attribute__((ext_vector_type(4)));
typedef float f32x4 __attribute__((ext_vector_type(4)));
#define MFMA16(a, b, c) __builtin_amdgcn_mfma_f32_16x16x32_bf16(a, b, c, 0, 0, 0)

__device__ __forceinline__ short f2b(float f) {
    unsigned u = __builtin_bit_cast(unsigned, f);
    unsigned r = (u + 0x7fffu + ((u >> 16) & 1u)) >> 16;
    return (short)r;
}
__device__ __forceinline__ float b2f(short s) {
    unsigned u = ((unsigned)(unsigned short)s) << 16;
    return __builtin_bit_cast(float, u);
}

// ---------------- sort-by-part kernels ----------------

__global__ __launch_bounds__(256) void hist_k(const int* __restrict__ part,
                                              int* __restrict__ counts, int n) {
    __shared__ int s_c[P_N];
    if (threadIdx.x < P_N) s_c[threadIdx.x] = 0;
    __syncthreads();
    int g = blockIdx.x * 256 + threadIdx.x;
    if (g < n) atomicAdd(&s_c[part[g]], 1);
    __syncthreads();
    if (threadIdx.x < P_N) atomicAdd(&counts[threadIdx.x], s_c[threadIdx.x]);
}

__global__ void offs_k(const int* __restrict__ counts, int* __restrict__ offs) {
    if (threadIdx.x == 0) {
        int o = 0;
        for (int p = 0; p < P_N; ++p) {
            offs[p] = o;
            o += (counts[p] + 63) & ~63;   // pad each part segment to 64
        }
        offs[P_N] = o;
    }
}

__global__ __launch_bounds__(256) void scatter_k(const int* __restrict__ part,
                                                 const int* __restrict__ offs,
                                                 int* __restrict__ cursors,
                                                 int* __restrict__ perm, int n) {
    const int t = threadIdx.x;
    const int g = blockIdx.x * 256 + t;
    const int p = (g < n) ? part[g] : -1;
    const int lane = t & 63;
    const int wid = t >> 6;
    __shared__ int s_wc[4][P_N];
    __shared__ int s_base[P_N];
    const unsigned long long lmask = (1ull << lane) - 1ull;
    int myrank = 0;
    for (int pp = 0; pp < P_N; ++pp) {
        unsigned long long m = __ballot(p == pp);
        if (p == pp) myrank = __popcll(m & lmask);
        if (lane == 0) s_wc[wid][pp] = __popcll(m);
    }
    __syncthreads();
    if (t < P_N) {
        int tot = s_wc[0][t] + s_wc[1][t] + s_wc[2][t] + s_wc[3][t];
        s_base[t] = atomicAdd(&cursors[t], tot);
    }
    __syncthreads();
    if (g < n) {
        int pre = 0;
        #pragma unroll
        for (int w2 = 0; w2 < 4; ++w2) if (w2 < wid) pre += s_wc[w2][p];
        perm[offs[p] + s_base[p] + pre + myrank] = g;
    }
}

// ---------------- merged weight prep (1 launch) ----------------

__device__ __forceinline__ float mseg(int l, const float* __restrict__ src,
                                      int DIN, int DOUT, int NP, int pps) {
    const int pn = NP * 128;
    const int p = l / pn;
    const int r = l - p * pn;
    const int n = r >> 7, k = r & 127;
    return (n < DOUT && k < DIN) ? src[p * pps + k * DOUT + n] : 0.f;
}
__device__ __forceinline__ float cseg(int l, const float* __restrict__ src, int CIN) {
    const int per = 9 * 64 * CIN;
    const int ll = l / per;
    int rem = l - ll * per;
    const int tap = rem / (64 * CIN);
    rem -= tap * 64 * CIN;
    const int och = rem / CIN;
    const int ci = rem - och * CIN;
    return src[((ll * 64 + och) * CIN + ci) * 9 + tap];
}

__global__ __launch_bounds__(256) void prep_k(
        const float* __restrict__ m1wi, const float* __restrict__ m1wh,
        const float* __restrict__ m1wo, const float* __restrict__ m2wi,
        const float* __restrict__ m2wh, const float* __restrict__ m2wo,
        const float* __restrict__ cinw, const float* __restrict__ chw,
        short* __restrict__ wb) {
    const int idx = blockIdx.x * 256 + threadIdx.x;
    if (idx >= 651264) return;
    float v;
    if      (idx < 81920)  v = mseg(idx,          m1wi,         96, 128, 128, 12288);
    else if (idx < 163840) v = mseg(idx - 81920,  m1wh,        128, 128, 128, 32768);
    else if (idx < 245760) v = mseg(idx - 163840, m1wh + 16384,128, 128, 128, 32768);
    else if (idx < 256000) v = mseg(idx - 245760, m1wo,        128,  11,  16, 1408);
    else if (idx < 337920) v = mseg(idx - 256000, m2wi,        110, 128, 128, 14080);
    else if (idx < 419840) v = mseg(idx - 337920, m2wh,        128, 128, 128, 32768);
    else if (idx < 501760) v = mseg(idx - 419840, m2wh + 16384,128, 128, 128, 32768);
    else if (idx < 522240) v = mseg(idx - 501760, m2wo,        128,  32,  32, 4096);
    else if (idx < 540672) v = cseg(idx - 522240, cinw, 32);
    else                   v = cseg(idx - 540672, chw, 64);
    wb[idx] = f2b(v);
}

// ---------------- fused MLP1+MLP2 (bf16 MFMA, WAVE-LOCAL, no cross-wave deps) ----
// block = 64 threads (1 wave) = 64 gaussians, part-uniform (64-padded sort).
// Wave computes all 128 neurons for its 64 rows -> layer chaining is wave-local.
// x1 kept resident in A-fragment registers (A1, 48 VGPRs) across both MLPs.

template<int NKC, bool ACT>
__device__ __forceinline__ void wcompute(const short8 (&A)[4][NKC],
                                         const short* __restrict__ wt,
                                         const float* __restrict__ bias,
                                         short* dst) {
    const int ln = threadIdx.x & 15, lq = threadIdx.x >> 4;   // t in [0,64)
    #pragma unroll
    for (int nt = 0; nt < 8; ++nt) {
        short8 B[NKC];
        #pragma unroll
        for (int kc = 0; kc < NKC; ++kc)
            B[kc] = *(const short8*)(wt + (nt * 16 + ln) * 128 + kc * 32 + lq * 8);
        const float bs = bias[nt * 16 + ln];
        #pragma unroll
        for (int mt = 0; mt < 4; ++mt) {
            f32x4 acc = {bs, bs, bs, bs};
            #pragma unroll
            for (int kc = 0; kc < NKC; ++kc) acc = MFMA16(A[mt][kc], B[kc], acc);
            #pragma unroll
            for (int r = 0; r < 4; ++r) {
                float v = acc[r];
                if (ACT) v = fmaxf(v, 0.01f * v);
                dst[(mt * 16 + lq * 4 + r) * XP + nt * 16 + ln] = f2b(v);
            }
        }
    }
}

__device__ __forceinline__ void preload4(short8 (&A)[4][4], const short* s) {
    const int ln = threadIdx.x & 15, lq = threadIdx.x >> 4;
    #pragma unroll
    for (int mt = 0; mt < 4; ++mt)
        #pragma unroll
        for (int kc = 0; kc < 4; ++kc)
            A[mt][kc] = *(const short8*)(s + (mt * 16 + ln) * XP + kc * 32 + lq * 8);
}

__global__ __launch_bounds__(64, 2) void mlp_k(
        const float* __restrict__ latent_z, const float* __restrict__ latent_f,
        const float* __restrict__ cano,
        const short* __restrict__ wt1i, const float* __restrict__ b1i,
        const short* __restrict__ wt1h0, const short* __restrict__ wt1h1,
        const float* __restrict__ b1h,
        const short* __restrict__ wt1o, const float* __restrict__ b1o,
        const short* __restrict__ wt2i, const float* __restrict__ b2i,
        const short* __restrict__ wt2h0, const short* __restrict__ wt2h1,
        const float* __restrict__ b2h,
        const short* __restrict__ wt2o, const float* __restrict__ b2o,
        const int* __restrict__ uv_idx, const int* __restrict__ perm,
        const int* __restrict__ offs, const int* __restrict__ counts,
        unsigned short* __restrict__ uvmap /* [PIX][32] bf16 */) {
    __shared__ short s_h[64 * XP];     // 17.4 KB hidden tile (in-place)
    __shared__ short s_c4[64 * SP];    // 5.1 KB: cols 0..2 cano, 3..13 attrs, 14..31 zero
    __shared__ int s_g[64];
    __shared__ int s_uv[64];

    const int t = threadIdx.x;
    const int ln = t & 15, lq = t >> 4;
    const int pos0 = blockIdx.x * 64;
    if (pos0 >= offs[P_N]) return;
    int p = 0;
    #pragma unroll
    for (int q = 1; q < P_N; ++q) if (pos0 >= offs[q]) p = q;
    const int vend = offs[p] + counts[p];

    {
        const int pos = pos0 + t;
        const int g = (pos < vend) ? perm[pos] : -1;
        s_g[t] = g;
        s_uv[t] = (g >= 0) ? uv_idx[g] : 0;
    }
    // zero side tile
    for (int i = t; i < 64 * SP / 2; i += 64) ((int*)s_c4)[i] = 0;
    __syncthreads();

    // stage x1: cols 0..63 latent_f[p], 64..95 latent_z[g]; cano -> side cols 0..2
    for (int i = t; i < 64 * 16; i += 64) {
        const int g = i >> 4, k4 = (i & 15) * 4;
        const float4 v = *(const float4*)(latent_f + p * 64 + k4);
        short4v o = {f2b(v.x), f2b(v.y), f2b(v.z), f2b(v.w)};
        *(short4v*)(s_h + g * XP + k4) = o;
    }
    for (int i = t; i < 64 * 8; i += 64) {
        const int g = i >> 3, k4 = (i & 7) * 4;
        const int gg = s_g[g];
        short4v o = {0, 0, 0, 0};
        if (gg >= 0) {
            const float4 v = *(const float4*)(latent_z + gg * 32 + k4);
            o[0] = f2b(v.x); o[1] = f2b(v.y); o[2] = f2b(v.z); o[3] = f2b(v.w);
        }
        *(short4v*)(s_h + g * XP + 64 + k4) = o;
    }
    for (int i = t; i < 64 * 3; i += 64) {
        const int g = i / 3, k = i - g * 3;
        const int gg = s_g[g];
        s_c4[g * SP + k] = (gg >= 0) ? f2b(cano[gg * 3 + k]) : 0;
    }
    __syncthreads();

    // x1 A-frags resident for the whole kernel (reused by MLP2 L1)
    short8 A1[4][3];
    #pragma unroll
    for (int mt = 0; mt < 4; ++mt)
        #pragma unroll
        for (int kc = 0; kc < 3; ++kc)
            A1[mt][kc] = *(const short8*)(s_h + (mt * 16 + ln) * XP + kc * 32 + lq * 8);
    __syncthreads();

    // MLP1: 96 -> 128 -> 128 -> 128 -> 11
    wcompute<3, true>(A1, wt1i + p * 16384, b1i + p * 128, s_h);
    __syncthreads();
    {
        short8 Ah[4][4];
        preload4(Ah, s_h); __syncthreads();
        wcompute<4, true>(Ah, wt1h0 + p * 16384, b1h + (p * 2 + 0) * 128, s_h);
        __syncthreads();
        preload4(Ah, s_h); __syncthreads();
        wcompute<4, true>(Ah, wt1h1 + p * 16384, b1h + (p * 2 + 1) * 128, s_h);
        __syncthreads();
        // L1 out: 11 attrs -> side-tile cols 3..13
        preload4(Ah, s_h); __syncthreads();
        short8 B[4];
        #pragma unroll
        for (int kc = 0; kc < 4; ++kc)
            B[kc] = *(const short8*)(wt1o + p * 2048 + ln * 128 + kc * 32 + lq * 8);
        const float bs = (ln < 11) ? b1o[p * 11 + ln] : 0.f;
        #pragma unroll
        for (int mt = 0; mt < 4; ++mt) {
            f32x4 acc = {bs, bs, bs, bs};
            #pragma unroll
            for (int kc = 0; kc < 4; ++kc) acc = MFMA16(Ah[mt][kc], B[kc], acc);
            if (ln < 11) {
                #pragma unroll
                for (int r = 0; r < 4; ++r)
                    s_c4[(mt * 16 + lq * 4 + r) * SP + 3 + ln] = f2b(acc[r]);
            }
        }
    }
    __syncthreads();

    // MLP2: 110(pad 128) -> 128 -> 128 -> 128 -> 32
    {
        short8 A2[4][4];
        #pragma unroll
        for (int mt = 0; mt < 4; ++mt) {
            A2[mt][0] = A1[mt][0]; A2[mt][1] = A1[mt][1]; A2[mt][2] = A1[mt][2];
            A2[mt][3] = *(const short8*)(s_c4 + (mt * 16 + ln) * SP + lq * 8);
        }
        __syncthreads();
        wcompute<4, true>(A2, wt2i + p * 16384, b2i + p * 128, s_h);
    }
    __syncthreads();
    {
        short8 Ah[4][4];
        preload4(Ah, s_h); __syncthreads();
        wcompute<4, true>(Ah, wt2h0 + p * 16384, b2h + (p * 2 + 0) * 128, s_h);
        __syncthreads();
        preload4(Ah, s_h); __syncthreads();
        wcompute<4, true>(Ah, wt2h1 + p * 16384, b2h + (p * 2 + 1) * 128, s_h);
        __syncthreads();
        // L2 out: 32 -> scatter to uvmap NHWC bf16
        preload4(Ah, s_h);
        #pragma unroll
        for (int nt = 0; nt < 2; ++nt) {
            short8 B[4];
            #pragma unroll
            for (int kc = 0; kc < 4; ++kc)
                B[kc] = *(const short8*)(wt2o + p * 4096 + (nt * 16 + ln) * 128 + kc * 32 + lq * 8);
            const float bs = b2o[p * 32 + nt * 16 + ln];
            #pragma unroll
            for (int mt = 0; mt < 4; ++mt) {
                f32x4 acc = {bs, bs, bs, bs};
                #pragma unroll
                for (int kc = 0; kc < 4; ++kc) acc = MFMA16(Ah[mt][kc], B[kc], acc);
                #pragma unroll
                for (int r = 0; r < 4; ++r) {
                    const int m = mt * 16 + lq * 4 + r;
                    const int g = s_g[m];
                    if (g >= 0)
                        uvmap[s_uv[m] * 32 + nt * 16 + ln] = (unsigned short)f2b(acc[r]);
                }
            }
        }
    }
}

// ---------------- CNN (bf16 MFMA implicit GEMM) ----------------
// grid (16,32): 16x8 pixel tile; block = 128 thr (2 waves) -> 512 blocks.
// Wave = 4 pixel rows x ALL 64 och (acc[4][4]): max B-reuse (weights streamed
// per-tap from L2, 75 MB/layer total) and 4-way A-reuse from LDS.
// TRANS: 0 raw, 1 relu, 2 IN+relu.

template<int CIN, int TRANS, bool STATS>
__global__ __launch_bounds__(128, 2) void conv_k(
        const unsigned short* __restrict__ in,   // [PIX][CIN] bf16
        const short* __restrict__ wt,            // [9][64][CIN] bf16
        const float* __restrict__ bias,
        const float* __restrict__ psum, const float* __restrict__ psq,
        unsigned short* __restrict__ out,        // [PIX][64] bf16
        float* __restrict__ ssum, float* __restrict__ ssq) {
    constexpr int CS = CIN + 8;
    constexpr int NKC = CIN / 32;
    constexpr int RUNS = CIN / 8;
    __shared__ short s_in[10 * 18 * CS];
    __shared__ float s_mr[2][64];
    __shared__ float s_red[2][2][64];

    const int t = threadIdx.x;
    const int ln = t & 15, lq = (t >> 4) & 3;
    const int w2 = t >> 6;
    const int tx0 = blockIdx.x * 16, ty0 = blockIdx.y * 8;

    if (TRANS == 2 && t < 64) {
        const float m = psum[t] * (1.f / PIX);
        const float vv = psq[t] * (1.f / PIX) - m * m;
        s_mr[0][t] = m;
        s_mr[1][t] = rsqrtf(vv + 1e-5f);
    }
    if (TRANS == 2) __syncthreads();

    for (int i = t; i < 180 * RUNS; i += 128) {
        const int sp = i / RUNS, run = i - sp * RUNS;
        const int r = sp / 18, c = sp - r * 18;
        const int gy = ty0 + r - 1, gx = tx0 + c - 1;
        short* dst = &s_in[(r * 18 + c) * CS + run * 8];
        if (gy >= 0 && gy < 256 && gx >= 0 && gx < 256) {
            short8 v = *(const short8*)(in + ((gy * 256 + gx) * CIN + run * 8));
            if (TRANS == 0) {
                *(short8*)dst = v;
            } else {
                short8 o;
                #pragma unroll
                for (int j = 0; j < 8; ++j) {
                    float f = b2f(v[j]);
                    if (TRANS == 2) f = (f - s_mr[0][run * 8 + j]) * s_mr[1][run * 8 + j];
                    o[j] = f2b(fmaxf(f, 0.f));
                }
                *(short8*)dst = o;
            }
        } else {
            short8 z = {0, 0, 0, 0, 0, 0, 0, 0};
            *(short8*)dst = z;
        }
    }
    __syncthreads();

    f32x4 acc[4][4];
    {
        float bs[4];
        #pragma unroll
        for (int nt = 0; nt < 4; ++nt) bs[nt] = bias[nt * 16 + ln];
        #pragma unroll
        for (int mt = 0; mt < 4; ++mt)
            #pragma unroll
            for (int nt = 0; nt < 4; ++nt) {
                f32x4 a = {bs[nt], bs[nt], bs[nt], bs[nt]};
                acc[mt][nt] = a;
            }
    }

    #pragma unroll
    for (int tap = 0; tap < 9; ++tap) {
        const int dy = tap / 3, dx = tap - dy * 3;
        const short* wtap = wt + tap * 64 * CIN;
        #pragma unroll
        for (int kc = 0; kc < NKC; ++kc) {
            short8 B[4];
            #pragma unroll
            for (int nt = 0; nt < 4; ++nt)
                B[nt] = *(const short8*)(wtap + (nt * 16 + ln) * CIN + kc * 32 + lq * 8);
            short8 A[4];
            #pragma unroll
            for (int mt = 0; mt < 4; ++mt)
                A[mt] = *(const short8*)&s_in[((w2 * 4 + mt + dy) * 18 + ln + dx) * CS + kc * 32 + lq * 8];
            #pragma unroll
            for (int mt = 0; mt < 4; ++mt)
                #pragma unroll
                for (int nt = 0; nt < 4; ++nt)
                    acc[mt][nt] = MFMA16(A[mt], B[nt], acc[mt][nt]);
        }
    }

    #pragma unroll
    for (int nt = 0; nt < 4; ++nt) {
        float ls = 0.f, lsq = 0.f;
        #pragma unroll
        for (int mt = 0; mt < 4; ++mt) {
            const int gy = ty0 + w2 * 4 + mt;
            #pragma unroll
            for (int r = 0; r < 4; ++r) {
                const float v = acc[mt][nt][r];
                const int gx = tx0 + lq * 4 + r;
                out[(gy * 256 + gx) * 64 + nt * 16 + ln] = (unsigned short)f2b(v);
                if (STATS) { ls += v; lsq = fmaf(v, v, lsq); }
            }
        }
        if (STATS) {
            ls  += __shfl_xor(ls, 16, 64);
            ls  += __shfl_xor(ls, 32, 64);
            lsq += __shfl_xor(lsq, 16, 64);
            lsq += __shfl_xor(lsq, 32, 64);
            if (lq == 0 && (t & 32) == 0) {
                s_red[w2][0][nt * 16 + ln] = ls;
                s_red[w2][1][nt * 16 + ln] = lsq;
            }
        }
    }
    if (STATS) {
        __syncthreads();
        if (t < 64) {
            atomicAdd(&ssum[t], s_red[0][0][t] + s_red[1][0][t]);
            atomicAdd(&ssq[t],  s_red[0][1][t] + s_red[1][1][t]);
        }
    }
}

// conv_out: 3 och + sigmoid, input = IN (no relu), fp32 VALU, output CHW fp32
__global__ __launch_bounds__(128) void convout_k(
        const unsigned short* __restrict__ in,   // [PIX][64] bf16
        const float* __restrict__ w,             // cow [3][64][3][3]
        const float* __restrict__ bias,
        const float* __restrict__ psum, const float* __restrict__ psq,
        float* __restrict__ out) {
    constexpr int CS = 72;
    __shared__ short s_in[10 * 18 * CS];
    __shared__ float s_w[3][9][64];
    __shared__ float s_mr[2][64];

    const int t = threadIdx.x;
    const int tx0 = blockIdx.x * 16, ty0 = blockIdx.y * 8;
    if (t < 64) {
        const float m = psum[t] * (1.f / PIX);
        const float vv = psq[t] * (1.f / PIX) - m * m;
        s_mr[0][t] = m;
        s_mr[1][t] = rsqrtf(vv + 1e-5f);
    }
    __syncthreads();

    for (int i = t; i < 180 * 8; i += 128) {
        const int sp = i >> 3, run = i & 7;
        const int r = sp / 18, c = sp - r * 18;
        const int gy = ty0 + r - 1, gx = tx0 + c - 1;
        short* dst = &s_in[(r * 18 + c) * CS + run * 8];
        if (gy >= 0 && gy < 256 && gx >= 0 && gx < 256) {
            short8 v = *(const short8*)(in + ((gy * 256 + gx) * 64 + run * 8));
            short8 o;
            #pragma unroll
            for (int j = 0; j < 8; ++j) {
                const float f = (b2f(v[j]) - s_mr[0][run * 8 + j]) * s_mr[1][run * 8 + j];
                o[j] = f2b(f);
            }
            *(short8*)dst = o;
        } else {
            short8 z = {0, 0, 0, 0, 0, 0, 0, 0};
            *(short8*)dst = z;
        }
    }
    for (int i = t; i < 1728; i += 128) {
        const int o = i / 576;
        const int rem = i - o * 576;
        const int tap = rem >> 6;
        const int ci = rem & 63;
        s_w[o][tap][ci] = w[o * 576 + ci * 9 + tap];
    }
    __syncthreads();

    const int py = t >> 4, px = t & 15;
    float a0 = bias[0], a1 = bias[1], a2 = bias[2];
    for (int tap = 0; tap < 9; ++tap) {
        const int dy = tap / 3, dx = tap % 3;
        const short* rp = &s_in[((py + dy) * 18 + (px + dx)) * CS];
        #pragma unroll
        for (int c8 = 0; c8 < 8; ++c8) {
            short8 v = *(const short8*)(rp + c8 * 8);
            #pragma unroll
            for (int j = 0; j < 8; ++j) {
                const float f = b2f(v[j]);
                const int ci = c8 * 8 + j;
                a0 = fmaf(f, s_w[0][tap][ci], a0);
                a1 = fmaf(f, s_w[1][tap][ci], a1);
                a2 = fmaf(f, s_w[2][tap][ci], a2);
            }
        }
    }
    const int pix = (ty0 + py) * 256 + tx0 + px;
    out[pix]           = 1.f / (1.f + expf(-a0));
    out[PIX + pix]     = 1.f / (1.f + expf(-a1));
    out[2 * PIX + pix] = 1.f / (1.f + expf(-a2));
}

// ---------------- launch ----------------

extern "C" void kernel_launch(void* const* d_in, const int* in_sizes, int n_in,
                              void* d_out, int out_size, void* d_ws, size_t ws_size,
                              hipStream_t stream) {
    (void)in_sizes; (void)n_in; (void)out_size; (void)ws_size;
    const float* latent_z = (const float*)d_in[0];
    const float* latent_f = (const float*)d_in[1];
    const float* cano     = (const float*)d_in[2];
    const float* m1wi = (const float*)d_in[3];
    const float* m1bi = (const float*)d_in[4];
    const float* m1wh = (const float*)d_in[5];
    const float* m1bh = (const float*)d_in[6];
    const float* m1wo = (const float*)d_in[7];
    const float* m1bo = (const float*)d_in[8];
    const float* m2wi = (const float*)d_in[9];
    const float* m2bi = (const float*)d_in[10];
    const float* m2wh = (const float*)d_in[11];
    const float* m2bh = (const float*)d_in[12];
    const float* m2wo = (const float*)d_in[13];
    const float* m2bo = (const float*)d_in[14];
    const float* cinw = (const float*)d_in[15];
    const float* cinb = (const float*)d_in[16];
    const float* chw  = (const float*)d_in[17];
    const float* chb  = (const float*)d_in[18];
    const float* cow  = (const float*)d_in[19];
    const float* cob  = (const float*)d_in[20];
    const int* gs_part = (const int*)d_in[21];
    const int* uv_idx  = (const int*)d_in[22];

    float* ws = (float*)d_ws;
    unsigned short* actA = (unsigned short*)ws;                 // [PIX][64] bf16 = 8 MB
    unsigned short* actB = (unsigned short*)(ws + 2097152);     // [PIX][64] bf16 = 8 MB
    unsigned short* uvmap = actB;                               // [PIX][32] aliases actB head

    short* wb = (short*)(ws + 4194304);
    short* wt1i  = wb;                  // 81920
    short* wt1h0 = wb + 81920;
    short* wt1h1 = wb + 163840;
    short* wt1o  = wb + 245760;         // 10240
    short* wt2i  = wb + 256000;
    short* wt2h0 = wb + 337920;
    short* wt2h1 = wb + 419840;
    short* wt2o  = wb + 501760;         // 20480
    short* cwt_in  = wb + 522240;       // 18432
    short* cwt_hid = wb + 540672;       // 110592 (end 651264 shorts)

    float* small = ws + 4194304 + 330000;
    int* counts  = (int*)small;             // 8
    int* cursors = counts + 8;              // 8
    int* offs    = cursors + 8;             // 8
    float* ssum  = small + 32;              // 3*64
    float* ssq   = ssum + 192;
    int* perm    = (int*)(ssq + 192);       // up to 40320

    hipMemsetAsync(uvmap, 0, (size_t)PIX * 32 * sizeof(unsigned short), stream);
    hipMemsetAsync(small, 0, 1024 * sizeof(float), stream);

    hist_k<<<157, 256, 0, stream>>>(gs_part, counts, G_N);
    offs_k<<<1, 64, 0, stream>>>(counts, offs);
    scatter_k<<<157, 256, 0, stream>>>(gs_part, offs, cursors, perm, G_N);

    prep_k<<<2544, 256, 0, stream>>>(m1wi, m1wh, m1wo, m2wi, m2wh, m2wo, cinw, chw, wb);

    mlp_k<<<630, 64, 0, stream>>>(latent_z, latent_f, cano,
        wt1i, m1bi, wt1h0, wt1h1, m1bh, wt1o, m1bo,
        wt2i, m2bi, wt2h0, wt2h1, m2bh, wt2o, m2bo,
        uv_idx, perm, offs, counts, uvmap);

    dim3 cgrid(16, 32);
    // conv_in: uvmap(raw) -> actA
    conv_k<32, 0, false><<<cgrid, 128, 0, stream>>>(uvmap, cwt_in, cinb,
        nullptr, nullptr, actA, nullptr, nullptr);
    // hidden 0: relu(actA) -> actB, stats slot0
    conv_k<64, 1, true><<<cgrid, 128, 0, stream>>>(actA, cwt_hid, chb,
        nullptr, nullptr, actB, ssum, ssq);
    // hidden 1: relu(IN(actB)) -> actA, stats slot1
    conv_k<64, 2, true><<<cgrid, 128, 0, stream>>>(actB, cwt_hid + 36864, chb + 64,
        ssum, ssq, actA, ssum + 64, ssq + 64);
    // hidden 2: relu(IN(actA)) -> actB, stats slot2
    conv_k<64, 2, true><<<cgrid, 128, 0, stream>>>(actA, cwt_hid + 73728, chb + 128,
        ssum + 64, ssq + 64, actB, ssum + 128, ssq + 128);
    // conv_out: IN(actB) -> sigmoid -> d_out (CHW fp32)
    convout_k<<<cgrid, 128, 0, stream>>>(actB, cow, cob,
        ssum + 128, ssq + 128, (float*)d_out);
}